// Round 3
// baseline (5931.574 us; speedup 1.0000x reference)
//
#include <hip/hip_runtime.h>
#include <stdint.h>

// HARSpikingNet: T=128, B=512, D=512, H=2048, C=18
#define T_STEPS 128
#define BSZ     512
#define DDIM    512
#define HDIM    2048
#define CDIM    18

#define BT 64                       // b-tile per WG (lane = b-row)
#define HT 64                       // h-tile per WG (wave w owns h cols 8w..8w+7)
#define KC 32                       // k-chunk per stage
#define NCHUNK (T_STEPS * (DDIM / KC))  // 2048
#define XBUF_FLOATS (BT * KC)       // 2048 floats = 8 KB per buffer
#define NBUF 3

typedef const __attribute__((address_space(1))) void gv_t;
typedef __attribute__((address_space(3))) void lv_t;

// Fused input-GEMM (x @ W_in^T + b_in) + LIF scan; z at t=T-1 -> z_ws bytes.
// Broadcast-W structure: wave owns 8 h-cols, lane = b-row. All W ds_reads are
// wave-uniform -> LDS broadcast (~free bandwidth); only x reads move real LDS
// bytes (64 KB/chunk/WG vs 393 KB in the old 4x2 tile). x staged via
// global_load_lds(16B) into 3 rotating buffers, counted vmcnt(1) + s_barrier.
// x source-XOR-swizzled (seg ^= row&7) so compute reads are conflict-free.
__launch_bounds__(512, 2)
__global__ void snn_fused(const float* __restrict__ x,
                          const float* __restrict__ Win,
                          const float* __restrict__ bin,
                          unsigned char* __restrict__ z_ws) {
    __shared__ float Wb[HT * DDIM];            // [h][k] row-major, 131072 B
    __shared__ float Xs[NBUF * XBUF_FLOATS];   // 24576 B  (total 155648)

    const int tid  = threadIdx.x;
    const int lane = tid & 63;          // b-row
    const int wave = tid >> 6;          // 0..7 -> h cols h0+8w..8w+7
    const int b0   = blockIdx.x * BT;   // 8 b-tiles
    const int h0   = blockIdx.y * HT;   // 32 h-tiles

    // ---- One-time: W tile into LDS, same [h][k] layout as global (no transpose)
    #pragma unroll
    for (int m = 0; m < 16; ++m) {
        int idx = tid + 512 * m;                 // float4 index in 64x512 tile
        int r   = idx >> 7;                      // 128 float4 per row
        int c4  = idx & 127;
        float4 w = reinterpret_cast<const float4*>(Win + (size_t)(h0 + r) * DDIM)[c4];
        *reinterpret_cast<float4*>(&Wb[r * DDIM + c4 * 4]) = w;
    }

    float bias[8];
    #pragma unroll
    for (int j = 0; j < 8; ++j) bias[j] = bin[h0 + (wave << 3) + j];

    float v[8], acc[8], zz[8];
    #pragma unroll
    for (int j = 0; j < 8; ++j) { v[j] = 0.f; acc[j] = 0.f; zz[j] = 0.f; }

    // Staging: thread covers (row r=tid>>3, stored seg s=tid&7); fetches global
    // seg s^(r&7). Wave w's 64 lanes cover rows 8w..8w+7 -> LDS dst linear.
    const int sr = tid >> 3;
    const int sg = ((tid & 7) ^ (sr & 7)) << 2;           // float offset in row
    const float* xsrc_base = x + (size_t)(b0 + sr) * DDIM + sg;

    #define STAGE(c, bufi) do {                                                 \
        const int t_ = (c) >> 4, kc_ = (c) & 15;                                \
        const float* src_ = xsrc_base + (size_t)t_ * (BSZ * DDIM) + kc_ * KC;   \
        void* dst_ = (void*)(Xs + (bufi) * XBUF_FLOATS + (wave << 8));          \
        __builtin_amdgcn_global_load_lds((gv_t*)src_, (lv_t*)dst_, 16, 0, 0);   \
    } while (0)

    STAGE(0, 0);
    STAGE(1, 1);
    __syncthreads();   // Wb visible (also drains the two prologue stages)

    const int lkey = lane & 7;          // read-side swizzle key
    int buf = 0;

    for (int c = 0; c < NCHUNK; ++c) {
        asm volatile("s_waitcnt vmcnt(1)" ::: "memory");
        __builtin_amdgcn_s_barrier();
        __builtin_amdgcn_sched_barrier(0);

        if (c + 2 < NCHUNK) {
            int b2 = buf + 2; if (b2 >= NBUF) b2 -= NBUF;
            STAGE(c + 2, b2);
        }

        const float* xb = Xs + buf * XBUF_FLOATS + (lane << 5);   // my b-row
        const float* wb = Wb + (wave << 3) * DDIM + ((c & 15) << 5);

        #pragma unroll
        for (int kq = 0; kq < 8; ++kq) {
            float4 xv = *(const float4*)(xb + ((kq ^ lkey) << 2));  // k = kq*4..+3
            float4 w0 = *(const float4*)(wb + 0 * DDIM + (kq << 2)); // uniform -> bcast
            float4 w1 = *(const float4*)(wb + 1 * DDIM + (kq << 2));
            float4 w2 = *(const float4*)(wb + 2 * DDIM + (kq << 2));
            float4 w3 = *(const float4*)(wb + 3 * DDIM + (kq << 2));
            float4 w4 = *(const float4*)(wb + 4 * DDIM + (kq << 2));
            float4 w5 = *(const float4*)(wb + 5 * DDIM + (kq << 2));
            float4 w6 = *(const float4*)(wb + 6 * DDIM + (kq << 2));
            float4 w7 = *(const float4*)(wb + 7 * DDIM + (kq << 2));
            #define FMA4(j, W)                              \
                acc[j] = fmaf(xv.x, W.x, acc[j]);           \
                acc[j] = fmaf(xv.y, W.y, acc[j]);           \
                acc[j] = fmaf(xv.z, W.z, acc[j]);           \
                acc[j] = fmaf(xv.w, W.w, acc[j]);
            FMA4(0, w0) FMA4(1, w1) FMA4(2, w2) FMA4(3, w3)
            FMA4(4, w4) FMA4(5, w5) FMA4(6, w6) FMA4(7, w7)
            #undef FMA4
        }

        if ((c & 15) == 15) {            // end of timestep: LIF update
            #pragma unroll
            for (int j = 0; j < 8; ++j) {
                float vv = 0.9f * v[j] + (acc[j] + bias[j]);
                float z1 = vv > 1.0f ? 1.0f : 0.0f;
                v[j]  = vv - z1;
                zz[j] = z1;
                acc[j] = 0.0f;
            }
        }
        buf = (buf + 1 == NBUF) ? 0 : buf + 1;
    }
    #undef STAGE

    // ---- emit z at t = T-1: 8 bytes per thread, aligned
    union { unsigned char b[8]; uint2 u; } o;
    #pragma unroll
    for (int j = 0; j < 8; ++j) o.b[j] = (unsigned char)zz[j];
    *reinterpret_cast<uint2*>(z_ws + (size_t)(b0 + lane) * HDIM + h0 + (wave << 3)) = o.u;
}

// logits[b,c] = sum_h z[b,h] * W_out[c,h] + b_out[c]. One wave per (b,c).
__global__ void snn_out(const unsigned char* __restrict__ z,
                        const float* __restrict__ Wout,
                        const float* __restrict__ bout,
                        float* __restrict__ out) {
    int gtid = blockIdx.x * blockDim.x + threadIdx.x;
    int wv   = gtid >> 6;
    int lane = threadIdx.x & 63;
    if (wv >= BSZ * CDIM) return;
    int b = wv / CDIM;
    int c = wv % CDIM;

    const unsigned char* zr = z + (size_t)b * HDIM;
    const float* wr = Wout + (size_t)c * HDIM;
    float s = 0.0f;
    #pragma unroll
    for (int m = 0; m < HDIM / 64; ++m) {
        int h = lane + 64 * m;
        s = fmaf((float)zr[h], wr[h], s);
    }
    #pragma unroll
    for (int off = 32; off > 0; off >>= 1) s += __shfl_down(s, off, 64);
    if (lane == 0) out[(size_t)b * CDIM + c] = s + bout[c];
}

extern "C" void kernel_launch(void* const* d_in, const int* in_sizes, int n_in,
                              void* d_out, int out_size, void* d_ws, size_t ws_size,
                              hipStream_t stream) {
    const float* x    = (const float*)d_in[0];   // [128,512,512]
    const float* Win  = (const float*)d_in[1];   // [2048,512]
    const float* bin  = (const float*)d_in[2];   // [2048]
    const float* Wout = (const float*)d_in[3];   // [18,2048]
    const float* bout = (const float*)d_in[4];   // [18]
    float* out = (float*)d_out;                  // [512,18]

    unsigned char* z_ws = (unsigned char*)d_ws;  // [512,2048] bytes

    dim3 grid1(BSZ / BT, HDIM / HT);             // 8 x 32 = 256 WGs (1/CU)
    snn_fused<<<grid1, 512, 0, stream>>>(x, Win, bin, z_ws);

    int waves = BSZ * CDIM;                      // 9216
    int blocks2 = (waves * 64) / 256;            // 2304
    snn_out<<<blocks2, 256, 0, stream>>>(z_ws, Wout, bout, out);
}

// Round 5
// 2205.339 us; speedup vs baseline: 2.6896x; 2.6896x over previous
//
#include <hip/hip_runtime.h>
#include <stdint.h>

// HARSpikingNet: T=128, B=512, D=512, H=2048, C=18
#define T_STEPS 128
#define BSZ     512
#define DDIM    512
#define HDIM    2048
#define CDIM    18

#define TBLK 8                     // timesteps carried per pass
#define KC   32                    // k-chunk per stage
#define NPASS (T_STEPS / TBLK)     // 16
#define NKC   (DDIM / KC)          // 16
#define NCH   (NPASS * NKC)        // 256 chunk iterations
#define XBUF  (TBLK * 64 * KC)     // 16384 floats = 64 KB per buffer
#define WBUF  (64 * KC)            // 2048 floats  =  8 KB per buffer

typedef const __attribute__((address_space(1))) void gv_t;
typedef __attribute__((address_space(3))) void lv_t;

// Fused input-GEMM + LIF, fp32, bit-identical numerics to the verified
// rounds 1-3 pattern: per (b,h,t) a single fp32 accumulator over k ascending.
// T-blocked: acc[8t][8h] per thread (lane = b-row, wave owns 8 h-cols).
// W traffic: ONE ds_read_b128 per wave per kc (lane l holds W[l&7][l>>3]),
// values distributed via v_readlane -> SGPR -> v_fmac s-operand (LDS-free).
// x: staged per (pass,kc) via global_load_lds, double-buffered, XOR source
// swizzle (quad ^= row&7) for conflict-spread reads. 1 barrier + vmcnt(0)
// drain per kc (compute/kc ~9k cy >> load latency).
__launch_bounds__(512, 1)
__global__ void snn_fused(const float* __restrict__ x,
                          const float* __restrict__ Win,
                          const float* __restrict__ bin,
                          unsigned char* __restrict__ z_ws) {
    __shared__ float Xs[2 * XBUF];   // 131072 B
    __shared__ float Ws[2 * WBUF];   //  16384 B  (total 147456)

    const int tid  = threadIdx.x;
    const int lane = tid & 63;          // b-row within tile
    const int wave = tid >> 6;          // 0..7 -> h cols h0+8w..8w+7
    const int b0   = blockIdx.x * 64;   // 8 b-tiles
    const int h0   = blockIdx.y * 64;   // 32 h-tiles
    const int lkey = lane & 7;          // read-side x swizzle key

    // Staging geometry: thread covers (row srow, stored quad sseg).
    const int srow = tid >> 3;              // 0..63
    const int sseg = tid & 7;               // stored quad
    const int gseg = sseg ^ (srow & 7);     // global quad fetched (x swizzle)

    const float* xsrc0 = x   + (size_t)(b0 + srow) * DDIM + gseg * 4;
    const float* wsrc0 = Win + (size_t)(h0 + srow) * DDIM + sseg * 4;

    float bias[8];
    #pragma unroll
    for (int j = 0; j < 8; ++j) bias[j] = bin[h0 + wave * 8 + j];

    float acc[TBLK][8], v[8], zz[8];
    #pragma unroll
    for (int j = 0; j < 8; ++j) { v[j] = 0.0f; zz[j] = 0.0f; }
    #pragma unroll
    for (int t = 0; t < TBLK; ++t)
        #pragma unroll
        for (int j = 0; j < 8; ++j) acc[t][j] = 0.0f;

    // Stage chunk S (pass ps=S>>4, k-chunk cs=S&15) into buffer S&1.
    #define STAGE(S) do {                                                       \
        const int ps_ = (S) >> 4, cs_ = (S) & 15, bp_ = (S) & 1;                \
        _Pragma("unroll")                                                       \
        for (int i_ = 0; i_ < TBLK; ++i_) {                                     \
            const float* src_ = xsrc0 + (size_t)(ps_ * TBLK + i_) * (BSZ*DDIM)  \
                                + cs_ * KC;                                     \
            void* dst_ = (void*)(Xs + bp_ * XBUF + i_ * 2048 + (wave << 8));    \
            __builtin_amdgcn_global_load_lds((gv_t*)src_, (lv_t*)dst_, 16,0,0); \
        }                                                                       \
        {                                                                       \
            const float* src_ = wsrc0 + cs_ * KC;                               \
            void* dst_ = (void*)(Ws + bp_ * WBUF + (wave << 8));                \
            __builtin_amdgcn_global_load_lds((gv_t*)src_, (lv_t*)dst_, 16,0,0); \
        }                                                                       \
    } while (0)

    STAGE(0);

    int C = 0;
    for (int p = 0; p < NPASS; ++p) {
        #pragma unroll 1
        for (int c = 0; c < NKC; ++c, ++C) {
            asm volatile("s_waitcnt vmcnt(0)" ::: "memory");
            __builtin_amdgcn_s_barrier();
            __builtin_amdgcn_sched_barrier(0);

            if (C + 1 < NCH) STAGE(C + 1);

            const float* xb = Xs + (c & 1) * XBUF + lane * KC;
            const float* wb = Ws + (c & 1) * WBUF;

            // One b128 per wave: lane l holds W[wave*8 + (l&7)][quad l>>3]
            float4 wq = *(const float4*)(wb + (wave * 8 + lkey) * KC
                                            + (lane >> 3) * 4);

            #pragma unroll
            for (int q = 0; q < 8; ++q) {          // k-quads ascending
                float4 xv[TBLK];
                #pragma unroll
                for (int t = 0; t < TBLK; ++t)
                    xv[t] = *(const float4*)(xb + t * (64 * KC)
                                                + ((q ^ lkey) << 2));
                #pragma unroll
                for (int j = 0; j < 8; ++j) {      // h within wave
                    const int sl = q * 8 + j;      // source lane (compile-time)
                    float w0 = __uint_as_float(
                        __builtin_amdgcn_readlane(__float_as_uint(wq.x), sl));
                    float w1 = __uint_as_float(
                        __builtin_amdgcn_readlane(__float_as_uint(wq.y), sl));
                    float w2 = __uint_as_float(
                        __builtin_amdgcn_readlane(__float_as_uint(wq.z), sl));
                    float w3 = __uint_as_float(
                        __builtin_amdgcn_readlane(__float_as_uint(wq.w), sl));
                    #pragma unroll
                    for (int t = 0; t < TBLK; ++t) {
                        acc[t][j] = fmaf(xv[t].x, w0, acc[t][j]);
                        acc[t][j] = fmaf(xv[t].y, w1, acc[t][j]);
                        acc[t][j] = fmaf(xv[t].z, w2, acc[t][j]);
                        acc[t][j] = fmaf(xv[t].w, w3, acc[t][j]);
                    }
                }
            }
        }

        // ---- LIF for this pass's 8 timesteps (t ascending, v carried)
        #pragma unroll
        for (int t = 0; t < TBLK; ++t)
            #pragma unroll
            for (int j = 0; j < 8; ++j) {
                float vv = 0.9f * v[j] + (acc[t][j] + bias[j]);
                float z1 = vv > 1.0f ? 1.0f : 0.0f;
                v[j]  = vv - z1;
                zz[j] = z1;
                acc[t][j] = 0.0f;
            }
    }
    #undef STAGE

    // ---- emit z at t = T-1: 8 bytes per thread, aligned
    union { unsigned char b[8]; uint2 u; } o;
    #pragma unroll
    for (int j = 0; j < 8; ++j) o.b[j] = (unsigned char)zz[j];
    *reinterpret_cast<uint2*>(z_ws + (size_t)(b0 + lane) * HDIM
                              + h0 + (wave << 3)) = o.u;
}

// logits[b,c] = sum_h z[b,h] * W_out[c,h] + b_out[c]. One wave per (b,c).
__global__ void snn_out(const unsigned char* __restrict__ z,
                        const float* __restrict__ Wout,
                        const float* __restrict__ bout,
                        float* __restrict__ out) {
    int gtid = blockIdx.x * blockDim.x + threadIdx.x;
    int wv   = gtid >> 6;
    int lane = threadIdx.x & 63;
    if (wv >= BSZ * CDIM) return;
    int b = wv / CDIM;
    int c = wv % CDIM;

    const unsigned char* zr = z + (size_t)b * HDIM;
    const float* wr = Wout + (size_t)c * HDIM;
    float s = 0.0f;
    #pragma unroll
    for (int m = 0; m < HDIM / 64; ++m) {
        int h = lane + 64 * m;
        s = fmaf((float)zr[h], wr[h], s);
    }
    #pragma unroll
    for (int off = 32; off > 0; off >>= 1) s += __shfl_down(s, off, 64);
    if (lane == 0) out[(size_t)b * CDIM + c] = s + bout[c];
}

extern "C" void kernel_launch(void* const* d_in, const int* in_sizes, int n_in,
                              void* d_out, int out_size, void* d_ws, size_t ws_size,
                              hipStream_t stream) {
    const float* x    = (const float*)d_in[0];   // [128,512,512]
    const float* Win  = (const float*)d_in[1];   // [2048,512]
    const float* bin  = (const float*)d_in[2];   // [2048]
    const float* Wout = (const float*)d_in[3];   // [18,2048]
    const float* bout = (const float*)d_in[4];   // [18]
    float* out = (float*)d_out;                  // [512,18]

    unsigned char* z_ws = (unsigned char*)d_ws;  // [512,2048] bytes

    dim3 grid1(BSZ / 64, HDIM / 64);             // 8 x 32 = 256 WGs (1/CU)
    snn_fused<<<grid1, 512, 0, stream>>>(x, Win, bin, z_ws);

    int waves = BSZ * CDIM;                      // 9216
    int blocks2 = (waves * 64) / 256;            // 2304
    snn_out<<<blocks2, 256, 0, stream>>>(z_ws, Wout, bout, out);
}